// Round 6
// baseline (236.368 us; speedup 1.0000x reference)
//
#include <hip/hip_runtime.h>

#define NBINS 128
#define NB2   (NBINS * NBINS)
#define TPB   256             // 4 waves
#define KC    32              // points per chunk
#define NBUCK 64              // 8x8 buckets of 16 bins each
#define CAPMIN 61000          // required per-bucket capacity (max bucket ~58.3k)
#define DNBLK 512             // dense fallback grid
#define DIMSH 4128            // dense fallback tile shorts (128*32 + 32 pad)

typedef __attribute__((ext_vector_type(8)))  short short8;
typedef __attribute__((ext_vector_type(16))) float f32x16;

// native 2^x (v_exp_f32); inputs finite
__device__ __forceinline__ float exp2_fast(float x) {
#if defined(__has_builtin)
#if __has_builtin(__builtin_amdgcn_exp2f)
    return __builtin_amdgcn_exp2f(x);
#else
    return exp2f(x);
#endif
#else
    return exp2f(x);
#endif
}

// pack two fp32 -> two bf16 (round-half-up) in one v_perm: [bf16(b) : bf16(a)]
__device__ __forceinline__ unsigned pk_bf16(float a, float b) {
    const unsigned ar = __float_as_uint(a) + 0x8000u;
    const unsigned br = __float_as_uint(b) + 0x8000u;
    return __builtin_amdgcn_perm(br, ar, 0x07060302u);
}

// C = -0.5*log2(e): weight(d) = exp(-0.5 d^2) = exp2(WC d^2)
#define WC (-0.72134752044448170f)
#define E1 (0.36787944117144233f)   // ratio-of-ratios decay e^-1

// byte-swizzle so b128 reads at row=l31 hit every bank exactly 8x and gen's
// paired b32 writes stay 2-way (free). Verified in R5 (passed refcheck).
__device__ __forceinline__ int swz(int r) {
    return ((r & 3) << 4) ^ ((r & 4) << 3) ^ ((r & 8) << 1);
}

// relaxed-atomic generation barrier; all cross-block data moves via
// agent-scope atomics (write-through), so NO cache fence is needed
// (R2 lesson: __threadfence = L2 writeback storm, -68us).
__device__ __forceinline__ void gbar(unsigned* ctr, unsigned target) {
    __syncthreads();
    if (threadIdx.x == 0) {
        __hip_atomic_fetch_add(ctr, 1u, __ATOMIC_RELAXED, __HIP_MEMORY_SCOPE_AGENT);
        while (__hip_atomic_load(ctr, __ATOMIC_RELAXED, __HIP_MEMORY_SCOPE_AGENT) < target)
            __builtin_amdgcn_s_sleep(16);
    }
    __syncthreads();
}

// ---------------------------------------------------------------------------
// Bucketed KDE v2. R5 diseases fixed, compute core unchanged:
//  - P4 work assigned per BLOCK (CPB = ceil(totalch/(grid-64))): ~95% blocks
//    busy (R5: 24% of waves), serial depth/wave 16 -> ~4 chunks, 16 busy
//    waves/CU hide the agent-load latency.
//  - 4 waves merge their 32x32 regions in 16KB LDS; ONE coalesced 4KB atomic
//    flush per block (R5: one 4KB scattered flush per wave).
//  - global cursors padded to 1/cacheline (R5: 65536 RMWs on 2 lines).
//  - storage reads agent-scope (stale-L2 hazard across graph replays).
// ws: [0]=sum f32, [16]=barrier ctr, [64+16b]=cursor b (64B stride),
//     byte 8192+: float2 storage, NBUCK regions of `cap` points.
// ---------------------------------------------------------------------------
__global__ __launch_bounds__(TPB, 4) void kde_bucket_kernel(
    const float* __restrict__ x,
    const float* __restrict__ ex,
    const float* __restrict__ ey,
    float* __restrict__ out,
    unsigned* __restrict__ wsu,
    int n, int cap)
{
    __shared__ __align__(16) char tl[4][4224];  // per wave: A 2048|pad|B 2048|pad
    __shared__ __align__(16) float mg[4][1024]; // per-wave 32x32 merge regions
    __shared__ unsigned sc[NBUCK];
    __shared__ unsigned cl[NBUCK];
    __shared__ float red[4];

    const int tid = (int)threadIdx.x, blk = (int)blockIdx.x, grid = (int)gridDim.x;
    const int lane = tid & 63, wv = tid >> 6;
    const int half = lane >> 5, l31 = lane & 31;
    unsigned* ctr  = wsu + 16;
    unsigned* gcur = wsu + 64;                        // stride 16 u32 (64B)
    const unsigned long long* storu =
        (const unsigned long long*)((char*)wsu + 8192);
    float2* stor = (float2*)((char*)wsu + 8192);

    const float lox = ex[0], loy = ey[0];
    const float ibx = 1.0f / (ex[1] - ex[0]);
    const float iby = 1.0f / (ey[1] - ey[0]);

    // P0: zero out with agent-scope stores (memory-side atomics must see it)
    for (int i = blk * TPB + tid; i < NB2; i += grid * TPB)
        __hip_atomic_store(&out[i], 0.f, __ATOMIC_RELAXED, __HIP_MEMORY_SCOPE_AGENT);

    // P1: count my point-slice per bucket (LDS), reserve global ranges
    if (tid < NBUCK) sc[tid] = 0;
    __syncthreads();
    const int slice = (n + grid - 1) / grid;
    const int p0 = blk * slice, p1 = min(n, p0 + slice);
    for (int p = p0 + tid; p < p1; p += TPB) {
        const float2 xy = *(const float2*)(x + (size_t)p * 6);
        const float uu = (xy.x - lox) * ibx - 0.5f;
        const float vv = (xy.y - loy) * iby - 0.5f;
        const int bu = min(7, max(0, ((int)uu) >> 4));
        const int bv = min(7, max(0, ((int)vv) >> 4));
        atomicAdd(&sc[(bu << 3) | bv], 1u);
    }
    __syncthreads();
    if (tid < NBUCK) sc[tid] = atomicAdd(&gcur[tid * 16], sc[tid]);
    __syncthreads();

    // P3: scatter (u,v); agent-scope 8B stores (write-through, no flush needed)
    for (int p = p0 + tid; p < p1; p += TPB) {
        const float2 xy = *(const float2*)(x + (size_t)p * 6);
        const float uu = (xy.x - lox) * ibx - 0.5f;
        const float vv = (xy.y - loy) * iby - 0.5f;
        const int bu = min(7, max(0, ((int)uu) >> 4));
        const int bv = min(7, max(0, ((int)vv) >> 4));
        const int bkt = (bu << 3) | bv;
        const unsigned slot = atomicAdd(&sc[bkt], 1u);
        if (slot < (unsigned)cap) {
            union { float2 f2; unsigned long long u8; } cv;
            cv.f2 = make_float2(uu, vv);
            __hip_atomic_store((unsigned long long*)(stor + (size_t)bkt * cap + slot),
                               cv.u8, __ATOMIC_RELAXED, __HIP_MEMORY_SCOPE_AGENT);
        }
    }

    gbar(ctr, (unsigned)grid);   // counts + storage + out-zeros now global

    // P4: block-granular assignment over the global chunk list
    if (tid < NBUCK) cl[tid] = __hip_atomic_load(&gcur[tid * 16], __ATOMIC_RELAXED,
                                                 __HIP_MEMORY_SCOPE_AGENT);
    __syncthreads();

    int totalch = 0;
    #pragma unroll 1
    for (int b = 0; b < NBUCK; ++b)
        totalch += (min((int)cl[b], cap) + (KC - 1)) >> 5;
    const int denom = max(1, grid - NBUCK);     // headroom: sum ceil <= grid
    int CPB = (totalch + denom - 1) / denom;
    if (CPB < 4) CPB = 4;

    int myb = -1, ca0 = 0, cb0 = 0, cum = 0;
    #pragma unroll 1
    for (int b = 0; b < NBUCK; ++b) {
        const int nch = (min((int)cl[b], cap) + (KC - 1)) >> 5;
        const int W = (nch + CPB - 1) / CPB;
        if (blk >= cum && blk < cum + W) {
            myb = b; ca0 = (blk - cum) * CPB; cb0 = min(nch, ca0 + CPB);
        }
        cum += W;
    }

    if (myb >= 0) {
        f32x16 acc;
        #pragma unroll
        for (int r = 0; r < 16; ++r) acc[r] = 0.f;

        const int pI = lane & 15, dimi = (lane >> 4) & 1, band = lane >> 5;
        const float ccf = (float)(((dimi ? (myb & 7) : (myb >> 3)) + band) << 4);
        char* tbd = &tl[wv][0] + dimi * 2112 + (8 + 16 * band) * 64;
        const char* tA = &tl[wv][0];
        const char* tB = &tl[wv][0] + 2112;
        const int sr = swz(l31 & 15);
        const int p4o = pI << 2;
        const int cntb = min((int)cl[myb], cap);
        const unsigned long long* sb = storu + (size_t)myb * cap;
        const int SW[8] = {16, 0, 48, 32, 48, 32, 16, 0};

        // waves round-robin the block's chunk range: serial depth ~CPB/4
        for (int c = ca0 + wv; c < cb0; c += 4) {
            const int valid = cntb - c * KC;
            float u0 = 3e9f, u1 = 3e9f;    // pad -> clamp -> zero weights
            if (2 * pI < valid) {
                union { float2 f2; unsigned long long u8; } cv;
                cv.u8 = __hip_atomic_load(sb + c * KC + 2 * pI,
                                          __ATOMIC_RELAXED, __HIP_MEMORY_SCOPE_AGENT);
                u0 = dimi ? cv.f2.y : cv.f2.x;
            }
            if (2 * pI + 1 < valid) {
                union { float2 f2; unsigned long long u8; } cv;
                cv.u8 = __hip_atomic_load(sb + c * KC + 2 * pI + 1,
                                          __ATOMIC_RELAXED, __HIP_MEMORY_SCOPE_AGENT);
                u1 = dimi ? cv.f2.y : cv.f2.x;
            }
            // Gaussian ratio recurrence, swept outward from the band center
            const float d0 = fminf(fmaxf(u0 - ccf, -88.f), 88.f);
            const float d1 = fminf(fmaxf(u1 - ccf, -88.f), 88.f);
            const float w0 = exp2_fast((WC * d0) * d0);
            const float w1 = exp2_fast((WC * d1) * d1);
            float r0 = exp2_fast(fmaf(-2.f * WC, d0, WC));
            float r1 = exp2_fast(fmaf(-2.f * WC, d1, WC));
            float q0 = exp2_fast(fmaf( 2.f * WC, d0, WC));
            float q1 = exp2_fast(fmaf( 2.f * WC, d1, WC));
            float a0 = w0, a1 = w1;
            #pragma unroll
            for (int j = 0; j < 8; ++j) {          // up: tile rows center..+7
                *(unsigned*)(tbd + j * 64 + (p4o ^ SW[j])) = pk_bf16(a0, a1);
                a0 *= r0; r0 *= E1;
                a1 *= r1; r1 *= E1;
            }
            a0 = w0; a1 = w1;
            #pragma unroll
            for (int j = 1; j <= 8; ++j) {         // down: center-1..-8
                a0 *= q0; a1 *= q1;
                *(unsigned*)(tbd - j * 64 + (p4o ^ SW[j - 1])) = pk_bf16(a0, a1);
                q0 *= E1; q1 *= E1;
            }
            // wave-private tile: in-order LDS per wave, no barriers needed
            #pragma unroll
            for (int s4 = 0; s4 < 2; ++s4) {
                const int kb2 = s4 * 32 + half * 16;
                const short8 av = *(const short8*)(tA + l31 * 64 + (kb2 ^ sr));
                const short8 bv = *(const short8*)(tB + l31 * 64 + (kb2 ^ sr));
                acc = __builtin_amdgcn_mfma_f32_32x32x16_bf16(av, bv, acc, 0, 0, 0);
            }
        }
        // park this wave's region in LDS; C/D layout col=l31,
        // row=(r&3)+8*(r>>2)+4*half (verified R6/R5)
        #pragma unroll
        for (int r = 0; r < 16; ++r) {
            const int rr = (r & 3) + 8 * (r >> 2) + 4 * half;
            mg[wv][rr * 32 + l31] = acc[r];
        }
    }
    __syncthreads();

    // merge 4 waves + ONE coalesced 4KB atomic flush per block
    float bsum = 0.f;
    if (myb >= 0) {
        float4 s = make_float4(0.f, 0.f, 0.f, 0.f);
        #pragma unroll
        for (int w = 0; w < 4; ++w) {
            const float4 t = ((const float4*)mg[w])[tid];
            s.x += t.x; s.y += t.y; s.z += t.z; s.w += t.w;
        }
        const int rr  = tid >> 3;                 // region row (32 floats/row)
        const int cc0 = (tid << 2) & 31;          // region col of s.x
        const int row  = ((myb >> 3) << 4) - 8 + rr;
        const int colb = ((myb & 7) << 4) - 8 + cc0;
        if ((unsigned)row < (unsigned)NBINS) {
            const float comp[4] = {s.x, s.y, s.z, s.w};
            #pragma unroll
            for (int k = 0; k < 4; ++k) {
                const int col = colb + k;
                if ((unsigned)col < (unsigned)NBINS) {
                    unsafeAtomicAdd(&out[row * NBINS + col], comp[k]);
                    bsum += comp[k];
                }
            }
        }
    }
    #pragma unroll
    for (int off = 32; off > 0; off >>= 1) bsum += __shfl_down(bsum, off, 64);
    if (lane == 0) red[wv] = bsum;
    __syncthreads();
    if (tid == 0) {
        const float t = red[0] + red[1] + red[2] + red[3];
        if (t != 0.f) unsafeAtomicAdd((float*)&wsu[0], t);
    }

    gbar(ctr, 2u * (unsigned)grid);   // all region atomics + sum complete

    // P5: normalize (agent loads bypass stale L2; plain final store)
    const float S = __hip_atomic_load((const float*)&wsu[0], __ATOMIC_RELAXED,
                                      __HIP_MEMORY_SCOPE_AGENT);
    const float inv = (S > 0.f) ? ibx * iby / S : 0.f;
    for (int i = blk * TPB + tid; i < NB2; i += grid * TPB) {
        const float v = __hip_atomic_load(&out[i], __ATOMIC_RELAXED,
                                          __HIP_MEMORY_SCOPE_AGENT);
        out[i] = v * inv;
    }
}

// ---------------------------------------------------------------------------
// Dense fallback (R3-proven main loop), used only if ws is too small.
// ---------------------------------------------------------------------------
__global__ __launch_bounds__(TPB, 4) void kde_dense_kernel(
    const float* __restrict__ x,
    const float* __restrict__ ex,
    const float* __restrict__ ey,
    float* __restrict__ out,
    int n, int nchunks)
{
    __shared__ unsigned short tiles[2][2][DIMSH];
    __shared__ float uv[2][2][KC];

    const int tid  = (int)threadIdx.x;
    const int lane = tid & 63;
    const int half = lane >> 5;
    const int l31  = lane & 31;
    const int w4   = tid >> 6;
    const int rowblk = (w4 >> 1) * 64;
    const int colblk = (w4 & 1) * 64;
    const int nblk = (int)gridDim.x;

    const float lox = ex[0], loy = ey[0];
    const float ibx = 1.0f / (ex[1] - ex[0]);
    const float iby = 1.0f / (ey[1] - ey[0]);

    const int pI     = tid & 15;
    const int dimi   = (tid >> 4) & 1;
    const int eighth = tid >> 5;
    const int cI     = eighth * 16 + 8;
    const float cc   = (float)cI;

    f32x16 acc[2][2];
    #pragma unroll
    for (int a = 0; a < 2; ++a)
        #pragma unroll
        for (int c = 0; c < 2; ++c)
            #pragma unroll
            for (int r = 0; r < 16; ++r) acc[a][c][r] = 0.f;

    const int niter = (nchunks + nblk - 1) / nblk;

    float2 xy; bool ldv = false;
    auto ld_xy = [&](int jt) {
        ldv = false;
        if (tid < KC && jt < niter) {
            const int g = (int)blockIdx.x + jt * nblk;
            if (g < nchunks) {
                ldv = true;
                const int p = g * KC + tid;
                if (p < n) xy = *(const float2*)(x + (size_t)p * 6);
                else       xy = make_float2(3e9f, 3e9f);
            }
        }
    };
    auto write_uv = [&](int jt) {
        if (ldv) {
            uv[jt & 1][0][tid] = (xy.x - lox) * ibx - 0.5f;
            uv[jt & 1][1][tid] = (xy.y - loy) * iby - 0.5f;
        }
    };
    auto gen = [&](int jt) {
        const int g = (int)blockIdx.x + jt * nblk;
        if (g >= nchunks) return;
        const int bb = jt & 1;
        const float* uvp = uv[bb][dimi];
        const float u0 = uvp[2 * pI], u1 = uvp[2 * pI + 1];
        const float d0 = fminf(fmaxf(u0 - cc, -88.f), 88.f);
        const float d1 = fminf(fmaxf(u1 - cc, -88.f), 88.f);
        const float w0 = exp2_fast((WC * d0) * d0);
        const float w1 = exp2_fast((WC * d1) * d1);
        float r0 = exp2_fast(fmaf(-2.f * WC, d0, WC));
        float r1 = exp2_fast(fmaf(-2.f * WC, d1, WC));
        float q0 = exp2_fast(fmaf( 2.f * WC, d0, WC));
        float q1 = exp2_fast(fmaf( 2.f * WC, d1, WC));
        char* tb0 = (char*)&tiles[bb][dimi][0] + cI * 64;
        const int o0 = pI << 2;
        const int os[4] = { o0, o0 ^ 16, o0 ^ 32, o0 ^ 48 };
        float a0 = w0, a1 = w1;
        #pragma unroll
        for (int j = 0; j < 8; ++j) {
            *(unsigned*)(tb0 + j * 64 + os[j & 3]) = pk_bf16(a0, a1);
            a0 *= r0; r0 *= E1;
            a1 *= r1; r1 *= E1;
        }
        a0 = w0; a1 = w1;
        #pragma unroll
        for (int j = 1; j <= 8; ++j) {
            a0 *= q0; a1 *= q1;
            *(unsigned*)(tb0 - j * 64 + os[(4 - j) & 3]) = pk_bf16(a0, a1);
            q0 *= E1; q1 *= E1;
        }
    };
    auto domfma = [&](int it) {
        const int g = (int)blockIdx.x + it * nblk;
        if (g >= nchunks) return;
        const int bb = it & 1;
        const char* Ab = (const char*)&tiles[bb][0][0];
        const char* Bb = (const char*)&tiles[bb][1][0];
        const int ra = rowblk + l31, cA = colblk + l31;
        const int sa = (ra & 3) << 4, sb = (cA & 3) << 4;
        #pragma unroll
        for (int s4 = 0; s4 < 2; ++s4) {
            const int kb2 = s4 * 32 + half * 16;
            const short8 a0 = *(const short8*)(Ab + ra * 64        + (kb2 ^ sa));
            const short8 a1 = *(const short8*)(Ab + (ra + 32) * 64 + (kb2 ^ sa));
            const short8 b0 = *(const short8*)(Bb + cA * 64        + (kb2 ^ sb));
            const short8 b1 = *(const short8*)(Bb + (cA + 32) * 64 + (kb2 ^ sb));
            acc[0][0] = __builtin_amdgcn_mfma_f32_32x32x16_bf16(a0, b0, acc[0][0], 0, 0, 0);
            acc[0][1] = __builtin_amdgcn_mfma_f32_32x32x16_bf16(a0, b1, acc[0][1], 0, 0, 0);
            acc[1][0] = __builtin_amdgcn_mfma_f32_32x32x16_bf16(a1, b0, acc[1][0], 0, 0, 0);
            acc[1][1] = __builtin_amdgcn_mfma_f32_32x32x16_bf16(a1, b1, acc[1][1], 0, 0, 0);
        }
    };

    ld_xy(0); write_uv(0);
    __syncthreads();
    ld_xy(1); gen(0); write_uv(1);
    __syncthreads();
    for (int it = 0; it < niter; ++it) {
        ld_xy(it + 2);
        domfma(it);
        gen(it + 1);
        write_uv(it + 2);
        __syncthreads();
    }

    #pragma unroll
    for (int rb = 0; rb < 2; ++rb)
        #pragma unroll
        for (int tj = 0; tj < 2; ++tj)
            #pragma unroll
            for (int r = 0; r < 16; ++r) {
                const int row = rowblk + rb * 32 + (r & 3) + 8 * (r >> 2) + 4 * half;
                const int col = colblk + tj * 32 + l31;
                unsafeAtomicAdd(&out[row * NBINS + col], acc[rb][tj][r]);
            }
}

__global__ __launch_bounds__(1024) void kde_final_kernel(
    float* __restrict__ out,
    const float* __restrict__ ex,
    const float* __restrict__ ey)
{
    __shared__ float red[1024 / 64];
    __shared__ float sinv;
    const int tid = (int)threadIdx.x;

    float4 v[4];
    float s = 0.f;
    #pragma unroll
    for (int i = 0; i < 4; ++i) {
        v[i] = ((const float4*)out)[tid + i * 1024];
        s += v[i].x + v[i].y + v[i].z + v[i].w;
    }
    #pragma unroll
    for (int off = 32; off > 0; off >>= 1) s += __shfl_down(s, off, 64);
    if ((tid & 63) == 0) red[tid >> 6] = s;
    __syncthreads();
    if (tid == 0) {
        float t = 0.f;
        #pragma unroll
        for (int i = 0; i < 1024 / 64; ++i) t += red[i];
        sinv = 1.0f / (t * (ex[1] - ex[0]) * (ey[1] - ey[0]));
    }
    __syncthreads();
    const float inv = sinv;
    #pragma unroll
    for (int i = 0; i < 4; ++i) {
        float4 o = v[i];
        o.x *= inv; o.y *= inv; o.z *= inv; o.w *= inv;
        ((float4*)out)[tid + i * 1024] = o;
    }
}

extern "C" void kernel_launch(void* const* d_in, const int* in_sizes, int n_in,
                              void* d_out, int out_size, void* d_ws, size_t ws_size,
                              hipStream_t stream)
{
    const float* x  = (const float*)d_in[0];
    const float* ex = (const float*)d_in[1];
    const float* ey = (const float*)d_in[2];
    float* out = (float*)d_out;
    const int n = in_sizes[0] / 6;

    long cap = 0;
    if (ws_size > 16384)
        cap = (long)((ws_size - 8192) / (NBUCK * sizeof(float2)));
    int maxb = 0;
    const hipError_t oe =
        hipOccupancyMaxActiveBlocksPerMultiprocessor(&maxb, kde_bucket_kernel, TPB, 0);

    if (oe == hipSuccess && maxb >= 1 && cap >= CAPMIN) {
        int grid = 256 * (maxb < 4 ? maxb : 4);   // guaranteed co-resident
        if (grid > 1024) grid = 1024;
        const int capi = (int)(cap > 0x3fffffffL ? 0x3fffffffL : cap);
        hipMemsetAsync(d_ws, 0, 8192, stream);    // sum + ctr + padded cursors
        kde_bucket_kernel<<<grid, TPB, 0, stream>>>(x, ex, ey, out,
                                                    (unsigned*)d_ws, n, capi);
    } else {
        const int nchunks = (n + KC - 1) / KC;
        hipMemsetAsync(d_out, 0, NB2 * sizeof(float), stream);
        kde_dense_kernel<<<DNBLK, TPB, 0, stream>>>(x, ex, ey, out, n, nchunks);
        kde_final_kernel<<<1, 1024, 0, stream>>>(out, ex, ey);
    }
}

// Round 8
// 103.576 us; speedup vs baseline: 2.2821x; 2.2821x over previous
//
#include <hip/hip_runtime.h>

#define NBINS 128
#define NB2   (NBINS * NBINS)
#define TPB   1024            // 16 waves = 4 teams x 4 quadrant-waves
#define NBLK  256             // 1 block/CU
#define KC    32              // points per chunk
#define NTEAM 4
#define ROWB  128             // combined tile row: 2 dims x 32 pts x bf16

typedef __attribute__((ext_vector_type(8)))  short short8;
typedef __attribute__((ext_vector_type(16))) float f32x16;

// native 2^x (v_exp_f32); inputs finite
__device__ __forceinline__ float exp2_fast(float x) {
#if defined(__has_builtin)
#if __has_builtin(__builtin_amdgcn_exp2f)
    return __builtin_amdgcn_exp2f(x);
#else
    return exp2f(x);
#endif
#else
    return exp2f(x);
#endif
}

// pack two fp32 -> two bf16 (round-half-up) in one v_perm: [bf16(b) : bf16(a)]
__device__ __forceinline__ unsigned pk_bf16(float a, float b) {
    const unsigned ar = __float_as_uint(a) + 0x8000u;
    const unsigned br = __float_as_uint(b) + 0x8000u;
    return __builtin_amdgcn_perm(br, ar, 0x07060302u);
}

// C = -0.5 * log2(e): weight(d) = exp(-0.5 d^2) = exp2(WC d^2)
#define WC (-0.72134752044448170f)
// ratio-of-ratios: w(m+1)/w(m) shrinks by 2^(2*WC) = e^-1 per step
#define E1 (0.36787944117144233f)

// LDS: double-buffered per-team COMBINED tiles, row = [dimA 64B | dimB 64B],
// XOR swizzle byte ^= (row&7)<<4 (R2 layout: bank conflicts 8M -> 2M vs the
// separate-tile R1 layout, counter-verified on identical work, refcheck'd).
// The 64 KB merge buffer aliases buf0 of the tiles (used only after the loop).
union __align__(16) ShMem {
    struct {
        unsigned short tiles[2][NTEAM][NBINS][2][KC]; // [buf][team][tap][dim][pt]
        float uv[2][NTEAM][2][KC];                    // [buf][team][dim][pt]
    } s;
    float hist[NB2];
};

// Kernel 1: hist = kx^T * ky as 128x128xK bf16 MFMA GEMM (R1 pipeline,
// R2 tile layout). Epilogue: merged block hist stored PLAIN + COALESCED into
// a per-block partial in ws (no 16MB device-atomic RMW: R3/R4 proved global
// f32 atomics write through at ~1.45 TB/s regardless of locality), plus ONE
// scalar atomicAdd per block for the normalization sum (computed for free
// while streaming the partial). No threadfence (R2 lesson), no spin anywhere.
__global__ __launch_bounds__(TPB, 4) void kde_mfma_kernel(
    const float* __restrict__ x,
    const float* __restrict__ ex,
    const float* __restrict__ ey,
    float* __restrict__ out,
    float* __restrict__ part,       // NBLK partial hists, or null (fallback)
    float* __restrict__ scal,       // [0]=sum f32 (memset 0 before launch)
    int n, int nchunks)
{
    __shared__ ShMem sm;
    __shared__ float wred[TPB / 64];

    const int tid  = (int)threadIdx.x;
    const int lane = tid & 63;
    const int half = lane >> 5;          // k-half of a 16-k step
    const int l31  = lane & 31;
    const int w4   = (tid >> 6) & 3;     // wave within team
    const int team = tid >> 8;           // 0..3
    const int rowblk = (w4 >> 1) * 64;
    const int colblk = (w4 & 1) * 64;

    const float lox = ex[0], loy = ey[0];
    const float ibx = 1.0f / (ex[1] - ex[0]);
    const float iby = 1.0f / (ey[1] - ey[0]);

    // weight-gen role: team-local thread -> (point-pair, dim, 16-tap band)
    const int tt     = tid & 255;
    const int pI     = tt & 15;          // point pair (points 2pI, 2pI+1)
    const int dimi   = (tt >> 4) & 1;    // 0 = x/A half, 1 = y/B half
    const int eighth = tt >> 5;          // tap band [16e, 16e+16)
    const int cI     = eighth * 16 + 8;  // band center row
    const float cc   = (float)cI;
    const int dimbase = dimi * 64 + pI * 4;  // byte offset within 128B row

    f32x16 acc[2][2];
    #pragma unroll
    for (int a = 0; a < 2; ++a)
        #pragma unroll
        for (int c = 0; c < 2; ++c)
            #pragma unroll
            for (int r = 0; r < 16; ++r) acc[a][c][r] = 0.f;

    const int niter = (nchunks + NBLK * NTEAM - 1) / (NBLK * NTEAM);

    // stage u/v for iteration jt into buffer jt&1 (threads 0..127)
    auto stage = [&](int jt) {
        if (tid < NTEAM * KC && jt < niter) {
            const int tm = tid >> 5, idx = tid & 31;
            const int g  = (int)blockIdx.x * NTEAM + tm + jt * (NBLK * NTEAM);
            if (g < nchunks) {
                const int p = g * KC + idx;
                float uu = 1e9f, vv = 1e9f;   // pad: clamp in gen -> zero weights
                if (p < n) {
                    const float2 xy = *(const float2*)(x + (size_t)p * 6);
                    uu = (xy.x - lox) * ibx - 0.5f;
                    vv = (xy.y - loy) * iby - 0.5f;
                }
                sm.s.uv[jt & 1][tm][0][idx] = uu;
                sm.s.uv[jt & 1][tm][1][idx] = vv;
            }
        }
    };

    // generate this thread's 16-tap band for iteration jt into tiles[jt&1].
    // Band swept outward from center c: w(c)=exp2(WC d^2),
    // up-ratio r=exp2(WC(1-2d)), down-ratio q=exp2(WC(1+2d)), both decay by E1.
    // clamp(d,+-88) keeps ratios finite for far/pad points (else 0*inf=NaN).
    auto gen = [&](int jt) {
        const int g = (int)blockIdx.x * NTEAM + team + jt * (NBLK * NTEAM);
        if (g >= nchunks) return;
        const int bb = jt & 1;
        const float* uvp = sm.s.uv[bb][team][dimi];
        const float u0 = uvp[2 * pI], u1 = uvp[2 * pI + 1];
        const float d0 = fminf(fmaxf(u0 - cc, -88.f), 88.f);
        const float d1 = fminf(fmaxf(u1 - cc, -88.f), 88.f);
        const float w0 = exp2_fast((WC * d0) * d0);
        const float w1 = exp2_fast((WC * d1) * d1);
        float r0 = exp2_fast(fmaf(-2.f * WC, d0, WC));
        float r1 = exp2_fast(fmaf(-2.f * WC, d1, WC));
        float q0 = exp2_fast(fmaf( 2.f * WC, d0, WC));
        float q1 = exp2_fast(fmaf( 2.f * WC, d1, WC));
        char* tb = (char*)&sm.s.tiles[bb][team][0][0][0];
        float a0 = w0, a1 = w1;
        #pragma unroll
        for (int j = 0; j < 8; ++j) {                   // up: row = c..c+7
            const int row = cI + j;
            *(unsigned*)(tb + row * ROWB + (dimbase ^ ((row & 7) << 4))) =
                pk_bf16(a0, a1);
            a0 *= r0; r0 *= E1;
            a1 *= r1; r1 *= E1;
        }
        a0 = w0; a1 = w1;
        #pragma unroll
        for (int j = 1; j <= 8; ++j) {                  // down: row = c-1..c-8
            const int row = cI - j;
            a0 *= q0; a1 *= q1;
            *(unsigned*)(tb + row * ROWB + (dimbase ^ ((row & 7) << 4))) =
                pk_bf16(a0, a1);
            q0 *= E1; q1 *= E1;
        }
    };

    // MFMA for iteration it from tiles[it&1]
    auto domfma = [&](int it) {
        const int g = (int)blockIdx.x * NTEAM + team + it * (NBLK * NTEAM);
        if (g >= nchunks) return;
        const int bb = it & 1;
        const char* tb = (const char*)&sm.s.tiles[bb][team][0][0][0];
        const int ra = rowblk + l31, ca = colblk + l31;
        const int sa = (ra & 7) << 4, sb = (ca & 7) << 4; // (r+32)&7 == r&7
        #pragma unroll
        for (int s4 = 0; s4 < 2; ++s4) {
            const int kb2 = s4 * 32 + half * 16;          // k-bytes within 64B half
            const short8 a0 = *(const short8*)(tb + ra * ROWB        + ( kb2       ^ sa));
            const short8 a1 = *(const short8*)(tb + (ra + 32) * ROWB + ( kb2       ^ sa));
            const short8 b0 = *(const short8*)(tb + ca * ROWB        + ((kb2 + 64) ^ sb));
            const short8 b1 = *(const short8*)(tb + (ca + 32) * ROWB + ((kb2 + 64) ^ sb));
            acc[0][0] = __builtin_amdgcn_mfma_f32_32x32x16_bf16(a0, b0, acc[0][0], 0, 0, 0);
            acc[0][1] = __builtin_amdgcn_mfma_f32_32x32x16_bf16(a0, b1, acc[0][1], 0, 0, 0);
            acc[1][0] = __builtin_amdgcn_mfma_f32_32x32x16_bf16(a1, b0, acc[1][0], 0, 0, 0);
            acc[1][1] = __builtin_amdgcn_mfma_f32_32x32x16_bf16(a1, b1, acc[1][1], 0, 0, 0);
        }
    };

    // software pipeline: one barrier per iteration; gen(it+1) and stage(it+2)
    // overlap domfma(it) on disjoint buffers.
    stage(0);
    __syncthreads();
    stage(1);
    gen(0);
    __syncthreads();
    for (int it = 0; it < niter; ++it) {
        stage(it + 2);
        domfma(it);
        gen(it + 1);
        __syncthreads();
    }
    // loop ends with a barrier: safe to alias tiles with hist now.

    // merge teams into LDS hist: 4 barrier-ordered passes of plain ds ops.
    // C/D layout (verified R6): row=(r&3)+8*(r>>2)+4*half, col=l31 per tile.
    for (int tm = 0; tm < NTEAM; ++tm) {
        if (team == tm) {
            #pragma unroll
            for (int rb = 0; rb < 2; ++rb)
                #pragma unroll
                for (int tj = 0; tj < 2; ++tj)
                    #pragma unroll
                    for (int r = 0; r < 16; ++r) {
                        const int row = rowblk + rb * 32 + (r & 3) + 8 * (r >> 2) + 4 * half;
                        const int col = colblk + tj * 32 + l31;
                        const int a = row * NBINS + col;
                        const float v = acc[rb][tj][r];
                        if (tm == 0) sm.hist[a] = v;
                        else         sm.hist[a] += v;
                    }
        }
        __syncthreads();
    }

    if (part) {
        // stream the block partial out (64 KB plain coalesced float4 stores)
        // and fold the block sum in the same pass (free ALU under stores).
        float4* dst = (float4*)(part + (size_t)blockIdx.x * NB2);
        const float4* src = (const float4*)sm.hist;
        float s = 0.f;
        for (int i = tid; i < NB2 / 4; i += TPB) {
            const float4 v = src[i];
            dst[i] = v;
            s += v.x + v.y + v.z + v.w;
        }
        #pragma unroll
        for (int off = 32; off > 0; off >>= 1) s += __shfl_down(s, off, 64);
        if (lane == 0) wred[tid >> 6] = s;
        __syncthreads();
        if (tid == 0) {
            float t = 0.f;
            #pragma unroll
            for (int i = 0; i < TPB / 64; ++i) t += wred[i];
            unsafeAtomicAdd(&scal[0], t);   // 256 scalar atomics total
        }
    } else {
        // fallback: device-atomic merge into out (zeroed host-side)
        for (int i = tid; i < NB2; i += TPB)
            unsafeAtomicAdd(&out[i], sm.hist[i]);
    }
}

// Kernel 2 (partials mode): 256 blocks; block b reduces output elements
// [64b, 64b+64) across the 256 partials (coalesced 256B runs, LLC-resident)
// and normalizes with the total sum computed by kernel 1 (scal[0] —
// visibility guaranteed by the dispatch boundary; no spin, no atomics).
__global__ __launch_bounds__(256) void kde_reduce_kernel(
    float* __restrict__ out,
    const float* __restrict__ part,
    const float* __restrict__ scal,
    const float* __restrict__ ex,
    const float* __restrict__ ey)
{
    __shared__ float smr[4][64];
    const int tid = (int)threadIdx.x, b = (int)blockIdx.x;
    const int g = tid >> 6, l = tid & 63;

    float v = 0.f;
    const float* base = part + b * 64 + l;
    #pragma unroll 4
    for (int p = g; p < NBLK; p += 4)
        v += base[(size_t)p * NB2];
    smr[g][l] = v;
    __syncthreads();

    if (g == 0) {
        const float tot = smr[0][l] + smr[1][l] + smr[2][l] + smr[3][l];
        const float inv = (1.0f / (ex[1] - ex[0])) * (1.0f / (ey[1] - ey[0]))
                        / scal[0];
        out[b * 64 + l] = tot * inv;
    }
}

// Kernel 2 (fallback mode): single block; total-reduce, normalize in place.
__global__ __launch_bounds__(1024) void kde_final_kernel(
    float* __restrict__ out,
    const float* __restrict__ ex,
    const float* __restrict__ ey)
{
    __shared__ float red[1024 / 64];
    __shared__ float sinv;
    const int tid = (int)threadIdx.x;

    float4 v[4];
    float s = 0.f;
    #pragma unroll
    for (int i = 0; i < 4; ++i) {
        v[i] = ((const float4*)out)[tid + i * 1024];
        s += v[i].x + v[i].y + v[i].z + v[i].w;
    }
    #pragma unroll
    for (int off = 32; off > 0; off >>= 1) s += __shfl_down(s, off, 64);
    if ((tid & 63) == 0) red[tid >> 6] = s;
    __syncthreads();
    if (tid == 0) {
        float t = 0.f;
        #pragma unroll
        for (int i = 0; i < 1024 / 64; ++i) t += red[i];
        sinv = 1.0f / (t * (ex[1] - ex[0]) * (ey[1] - ey[0]));
    }
    __syncthreads();
    const float inv = sinv;
    #pragma unroll
    for (int i = 0; i < 4; ++i) {
        float4 o = v[i];
        o.x *= inv; o.y *= inv; o.z *= inv; o.w *= inv;
        ((float4*)out)[tid + i * 1024] = o;
    }
}

extern "C" void kernel_launch(void* const* d_in, const int* in_sizes, int n_in,
                              void* d_out, int out_size, void* d_ws, size_t ws_size,
                              hipStream_t stream)
{
    const float* x  = (const float*)d_in[0];
    const float* ex = (const float*)d_in[1];
    const float* ey = (const float*)d_in[2];
    float* out = (float*)d_out;
    const int n = in_sizes[0] / 6;
    const int nchunks = (n + KC - 1) / KC;

    const size_t needPart = (size_t)NBLK * NB2 * sizeof(float) + 64;
    if (ws_size >= needPart) {
        float* part = (float*)d_ws;
        float* scal = part + (size_t)NBLK * NB2;
        hipMemsetAsync(scal, 0, sizeof(float), stream);   // sum accumulator
        kde_mfma_kernel<<<NBLK, TPB, 0, stream>>>(x, ex, ey, out, part, scal,
                                                  n, nchunks);
        kde_reduce_kernel<<<NBLK, 256, 0, stream>>>(out, part, scal, ex, ey);
    } else {
        hipMemsetAsync(d_out, 0, NB2 * sizeof(float), stream);
        kde_mfma_kernel<<<NBLK, TPB, 0, stream>>>(x, ex, ey, out,
                                                  nullptr, nullptr, n, nchunks);
        kde_final_kernel<<<1, 1024, 0, stream>>>(out, ex, ey);
    }
}

// Round 9
// 101.635 us; speedup vs baseline: 2.3257x; 1.0191x over previous
//
#include <hip/hip_runtime.h>

#define NBINS 128
#define NB2   (NBINS * NBINS)
#define TPB   1024            // 16 waves = 4 teams x 4 quadrant-waves
#define NBLK  256             // 1 block/CU
#define KC    32              // points per chunk
#define NTEAM 4
#define ROWB  128             // combined tile row: 2 dims x 32 pts x bf16

typedef __attribute__((ext_vector_type(8)))  short short8;
typedef __attribute__((ext_vector_type(16))) float f32x16;
typedef __attribute__((ext_vector_type(2)))  float f32x2;

// native 2^x (v_exp_f32); inputs finite
__device__ __forceinline__ float exp2_fast(float x) {
#if defined(__has_builtin)
#if __has_builtin(__builtin_amdgcn_exp2f)
    return __builtin_amdgcn_exp2f(x);
#else
    return exp2f(x);
#endif
#else
    return exp2f(x);
#endif
}

// packed fp32 multiply (VOP3P, CDNA): one instr for both lanes of the pair
__device__ __forceinline__ f32x2 pk_mul(f32x2 a, f32x2 b) {
    f32x2 d;
    asm("v_pk_mul_f32 %0, %1, %2" : "=v"(d) : "v"(a), "v"(b));
    return d;
}

// pack two fp32 -> two bf16 (round-half-up) in one v_perm: [bf16(b) : bf16(a)]
__device__ __forceinline__ unsigned pk_bf16(float a, float b) {
    const unsigned ar = __float_as_uint(a) + 0x8000u;
    const unsigned br = __float_as_uint(b) + 0x8000u;
    return __builtin_amdgcn_perm(br, ar, 0x07060302u);
}

// C = -0.5 * log2(e): weight(d) = exp(-0.5 d^2) = exp2(WC d^2)
#define WC (-0.72134752044448170f)
// ratio-of-ratios: w(m+1)/w(m) shrinks by 2^(2*WC) = e^-1 per step
#define E1 (0.36787944117144233f)

// LDS: double-buffered per-team COMBINED tiles, row = [dimA 64B | dimB 64B],
// XOR swizzle byte ^= (row&7)<<4 (R2 layout, counter-verified: conflicts
// 8M -> 2M vs separate tiles). 64 KB merge buffer aliases buf0 of the tiles.
union __align__(16) ShMem {
    struct {
        unsigned short tiles[2][NTEAM][NBINS][2][KC]; // [buf][team][tap][dim][pt]
        float uv[2][NTEAM][2][KC];                    // [buf][team][dim][pt]
    } s;
    float hist[NB2];
};

// Kernel 1: hist = kx^T * ky as 128x128xK bf16 MFMA GEMM (R1 pipeline,
// R2 tile layout, R8 plain-store epilogue — no 16MB atomic RMW; R3/R4 proved
// device atomics write through at ~1.45 TB/s regardless of locality).
// R9: packed-fp32 recurrence (v_pk_mul_f32 halves the hot-loop muls) and
// per-block sums via plain store (no atomic, no memset node).
__global__ __launch_bounds__(TPB, 4) void kde_mfma_kernel(
    const float* __restrict__ x,
    const float* __restrict__ ex,
    const float* __restrict__ ey,
    float* __restrict__ out,
    float* __restrict__ part,       // NBLK partial hists, or null (fallback)
    float* __restrict__ bsum,       // NBLK per-block sums (partials mode)
    int n, int nchunks)
{
    __shared__ ShMem sm;
    __shared__ float wred[TPB / 64];

    const int tid  = (int)threadIdx.x;
    const int lane = tid & 63;
    const int half = lane >> 5;          // k-half of a 16-k step
    const int l31  = lane & 31;
    const int w4   = (tid >> 6) & 3;     // wave within team
    const int team = tid >> 8;           // 0..3
    const int rowblk = (w4 >> 1) * 64;
    const int colblk = (w4 & 1) * 64;

    const float lox = ex[0], loy = ey[0];
    const float ibx = 1.0f / (ex[1] - ex[0]);
    const float iby = 1.0f / (ey[1] - ey[0]);

    // weight-gen role: team-local thread -> (point-pair, dim, 16-tap band)
    const int tt     = tid & 255;
    const int pI     = tt & 15;          // point pair (points 2pI, 2pI+1)
    const int dimi   = (tt >> 4) & 1;    // 0 = x/A half, 1 = y/B half
    const int eighth = tt >> 5;          // tap band [16e, 16e+16)
    const int cI     = eighth * 16 + 8;  // band center row
    const float cc   = (float)cI;
    const int dimbase = dimi * 64 + pI * 4;  // byte offset within 128B row

    f32x16 acc[2][2];
    #pragma unroll
    for (int a = 0; a < 2; ++a)
        #pragma unroll
        for (int c = 0; c < 2; ++c)
            #pragma unroll
            for (int r = 0; r < 16; ++r) acc[a][c][r] = 0.f;

    const int niter = (nchunks + NBLK * NTEAM - 1) / (NBLK * NTEAM);

    // stage u/v for iteration jt into buffer jt&1 (threads 0..127)
    auto stage = [&](int jt) {
        if (tid < NTEAM * KC && jt < niter) {
            const int tm = tid >> 5, idx = tid & 31;
            const int g  = (int)blockIdx.x * NTEAM + tm + jt * (NBLK * NTEAM);
            if (g < nchunks) {
                const int p = g * KC + idx;
                float uu = 1e9f, vv = 1e9f;   // pad: clamp in gen -> zero weights
                if (p < n) {
                    const float2 xy = *(const float2*)(x + (size_t)p * 6);
                    uu = (xy.x - lox) * ibx - 0.5f;
                    vv = (xy.y - loy) * iby - 0.5f;
                }
                sm.s.uv[jt & 1][tm][0][idx] = uu;
                sm.s.uv[jt & 1][tm][1][idx] = vv;
            }
        }
    };

    // generate this thread's 16-tap band for iteration jt into tiles[jt&1].
    // Band swept outward from center c: w(c)=exp2(WC d^2),
    // up-ratio r=exp2(WC(1-2d)), down-ratio q=exp2(WC(1+2d)), both decay by E1.
    // clamp(d,+-88) keeps ratios finite for far/pad points (else 0*inf=NaN).
    // Recurrence runs PACKED: {a0,a1}*={r0,r1}, {r0,r1}*={E1,E1} (2 instrs).
    auto gen = [&](int jt) {
        const int g = (int)blockIdx.x * NTEAM + team + jt * (NBLK * NTEAM);
        if (g >= nchunks) return;
        const int bb = jt & 1;
        const float* uvp = sm.s.uv[bb][team][dimi];
        const float u0 = uvp[2 * pI], u1 = uvp[2 * pI + 1];
        const float d0 = fminf(fmaxf(u0 - cc, -88.f), 88.f);
        const float d1 = fminf(fmaxf(u1 - cc, -88.f), 88.f);
        const float w0 = exp2_fast((WC * d0) * d0);
        const float w1 = exp2_fast((WC * d1) * d1);
        f32x2 A, R, Q;
        A.x = w0;                               A.y = w1;
        R.x = exp2_fast(fmaf(-2.f * WC, d0, WC)); R.y = exp2_fast(fmaf(-2.f * WC, d1, WC));
        Q.x = exp2_fast(fmaf( 2.f * WC, d0, WC)); Q.y = exp2_fast(fmaf( 2.f * WC, d1, WC));
        const f32x2 E = { E1, E1 };
        char* tb = (char*)&sm.s.tiles[bb][team][0][0][0];
        #pragma unroll
        for (int j = 0; j < 8; ++j) {                   // up: row = c..c+7
            const int row = cI + j;
            *(unsigned*)(tb + row * ROWB + (dimbase ^ ((row & 7) << 4))) =
                pk_bf16(A.x, A.y);
            A = pk_mul(A, R);
            R = pk_mul(R, E);
        }
        A.x = w0; A.y = w1;
        #pragma unroll
        for (int j = 1; j <= 8; ++j) {                  // down: row = c-1..c-8
            const int row = cI - j;
            A = pk_mul(A, Q);
            Q = pk_mul(Q, E);
            *(unsigned*)(tb + row * ROWB + (dimbase ^ ((row & 7) << 4))) =
                pk_bf16(A.x, A.y);
        }
    };

    // MFMA for iteration it from tiles[it&1]
    auto domfma = [&](int it) {
        const int g = (int)blockIdx.x * NTEAM + team + it * (NBLK * NTEAM);
        if (g >= nchunks) return;
        const int bb = it & 1;
        const char* tb = (const char*)&sm.s.tiles[bb][team][0][0][0];
        const int ra = rowblk + l31, ca = colblk + l31;
        const int sa = (ra & 7) << 4, sb = (ca & 7) << 4; // (r+32)&7 == r&7
        #pragma unroll
        for (int s4 = 0; s4 < 2; ++s4) {
            const int kb2 = s4 * 32 + half * 16;          // k-bytes within 64B half
            const short8 a0 = *(const short8*)(tb + ra * ROWB        + ( kb2       ^ sa));
            const short8 a1 = *(const short8*)(tb + (ra + 32) * ROWB + ( kb2       ^ sa));
            const short8 b0 = *(const short8*)(tb + ca * ROWB        + ((kb2 + 64) ^ sb));
            const short8 b1 = *(const short8*)(tb + (ca + 32) * ROWB + ((kb2 + 64) ^ sb));
            acc[0][0] = __builtin_amdgcn_mfma_f32_32x32x16_bf16(a0, b0, acc[0][0], 0, 0, 0);
            acc[0][1] = __builtin_amdgcn_mfma_f32_32x32x16_bf16(a0, b1, acc[0][1], 0, 0, 0);
            acc[1][0] = __builtin_amdgcn_mfma_f32_32x32x16_bf16(a1, b0, acc[1][0], 0, 0, 0);
            acc[1][1] = __builtin_amdgcn_mfma_f32_32x32x16_bf16(a1, b1, acc[1][1], 0, 0, 0);
        }
    };

    // software pipeline: one barrier per iteration; gen(it+1) and stage(it+2)
    // overlap domfma(it) on disjoint buffers.
    stage(0);
    __syncthreads();
    stage(1);
    gen(0);
    __syncthreads();
    for (int it = 0; it < niter; ++it) {
        stage(it + 2);
        domfma(it);
        gen(it + 1);
        __syncthreads();
    }
    // loop ends with a barrier: safe to alias tiles with hist now.

    // merge teams into LDS hist: 4 barrier-ordered passes of plain ds ops.
    // C/D layout (verified R6): row=(r&3)+8*(r>>2)+4*half, col=l31 per tile.
    for (int tm = 0; tm < NTEAM; ++tm) {
        if (team == tm) {
            #pragma unroll
            for (int rb = 0; rb < 2; ++rb)
                #pragma unroll
                for (int tj = 0; tj < 2; ++tj)
                    #pragma unroll
                    for (int r = 0; r < 16; ++r) {
                        const int row = rowblk + rb * 32 + (r & 3) + 8 * (r >> 2) + 4 * half;
                        const int col = colblk + tj * 32 + l31;
                        const int a = row * NBINS + col;
                        const float v = acc[rb][tj][r];
                        if (tm == 0) sm.hist[a] = v;
                        else         sm.hist[a] += v;
                    }
        }
        __syncthreads();
    }

    if (part) {
        // stream the block partial out (64 KB plain coalesced float4 stores)
        // and fold the block sum in the same pass (free ALU under stores);
        // block sum exits via ONE plain store (no atomic, no memset needed).
        float4* dst = (float4*)(part + (size_t)blockIdx.x * NB2);
        const float4* src = (const float4*)sm.hist;
        float s = 0.f;
        for (int i = tid; i < NB2 / 4; i += TPB) {
            const float4 v = src[i];
            dst[i] = v;
            s += v.x + v.y + v.z + v.w;
        }
        #pragma unroll
        for (int off = 32; off > 0; off >>= 1) s += __shfl_down(s, off, 64);
        if (lane == 0) wred[tid >> 6] = s;
        __syncthreads();
        if (tid == 0) {
            float t = 0.f;
            #pragma unroll
            for (int i = 0; i < TPB / 64; ++i) t += wred[i];
            bsum[blockIdx.x] = t;
        }
    } else {
        // fallback: device-atomic merge into out (zeroed host-side)
        for (int i = tid; i < NB2; i += TPB)
            unsafeAtomicAdd(&out[i], sm.hist[i]);
    }
}

// Kernel 2 (partials mode): 256 blocks; block b reduces output elements
// [64b, 64b+64) across the 256 partials (coalesced 256B runs, LLC-resident)
// and normalizes with the global sum folded from bsum[256] (1 KB, local
// reduce — no atomics, no spin; visibility via the dispatch boundary).
__global__ __launch_bounds__(256) void kde_reduce_kernel(
    float* __restrict__ out,
    const float* __restrict__ part,
    const float* __restrict__ bsum,
    const float* __restrict__ ex,
    const float* __restrict__ ey)
{
    __shared__ float smr[4][64];
    __shared__ float sred[4];
    const int tid = (int)threadIdx.x, b = (int)blockIdx.x;
    const int g = tid >> 6, l = tid & 63;

    // global sum from the 256 per-block sums
    float s = bsum[tid];
    #pragma unroll
    for (int off = 32; off > 0; off >>= 1) s += __shfl_down(s, off, 64);
    if (l == 0) sred[g] = s;

    float v = 0.f;
    const float* base = part + b * 64 + l;
    #pragma unroll 4
    for (int p = g; p < NBLK; p += 4)
        v += base[(size_t)p * NB2];
    smr[g][l] = v;
    __syncthreads();

    if (g == 0) {
        const float tot = smr[0][l] + smr[1][l] + smr[2][l] + smr[3][l];
        const float S = sred[0] + sred[1] + sred[2] + sred[3];
        const float inv = (1.0f / (ex[1] - ex[0])) * (1.0f / (ey[1] - ey[0])) / S;
        out[b * 64 + l] = tot * inv;
    }
}

// Kernel 2 (fallback mode): single block; total-reduce, normalize in place.
__global__ __launch_bounds__(1024) void kde_final_kernel(
    float* __restrict__ out,
    const float* __restrict__ ex,
    const float* __restrict__ ey)
{
    __shared__ float red[1024 / 64];
    __shared__ float sinv;
    const int tid = (int)threadIdx.x;

    float4 v[4];
    float s = 0.f;
    #pragma unroll
    for (int i = 0; i < 4; ++i) {
        v[i] = ((const float4*)out)[tid + i * 1024];
        s += v[i].x + v[i].y + v[i].z + v[i].w;
    }
    #pragma unroll
    for (int off = 32; off > 0; off >>= 1) s += __shfl_down(s, off, 64);
    if ((tid & 63) == 0) red[tid >> 6] = s;
    __syncthreads();
    if (tid == 0) {
        float t = 0.f;
        #pragma unroll
        for (int i = 0; i < 1024 / 64; ++i) t += red[i];
        sinv = 1.0f / (t * (ex[1] - ex[0]) * (ey[1] - ey[0]));
    }
    __syncthreads();
    const float inv = sinv;
    #pragma unroll
    for (int i = 0; i < 4; ++i) {
        float4 o = v[i];
        o.x *= inv; o.y *= inv; o.z *= inv; o.w *= inv;
        ((float4*)out)[tid + i * 1024] = o;
    }
}

extern "C" void kernel_launch(void* const* d_in, const int* in_sizes, int n_in,
                              void* d_out, int out_size, void* d_ws, size_t ws_size,
                              hipStream_t stream)
{
    const float* x  = (const float*)d_in[0];
    const float* ex = (const float*)d_in[1];
    const float* ey = (const float*)d_in[2];
    float* out = (float*)d_out;
    const int n = in_sizes[0] / 6;
    const int nchunks = (n + KC - 1) / KC;

    const size_t needPart = (size_t)NBLK * NB2 * sizeof(float)
                          + (size_t)NBLK * sizeof(float);
    if (ws_size >= needPart) {
        float* part = (float*)d_ws;
        float* bsum = part + (size_t)NBLK * NB2;
        kde_mfma_kernel<<<NBLK, TPB, 0, stream>>>(x, ex, ey, out, part, bsum,
                                                  n, nchunks);
        kde_reduce_kernel<<<NBLK, 256, 0, stream>>>(out, part, bsum, ex, ey);
    } else {
        hipMemsetAsync(d_out, 0, NB2 * sizeof(float), stream);
        kde_mfma_kernel<<<NBLK, TPB, 0, stream>>>(x, ex, ey, out,
                                                  nullptr, nullptr, n, nchunks);
        kde_final_kernel<<<1, 1024, 0, stream>>>(out, ex, ey);
    }
}